// Round 8
// baseline (708.457 us; speedup 1.0000x reference)
//
#include <hip/hip_runtime.h>

#define NN 50000     // nodes
#define NE 600000    // directed edges (self loops handled separately)
#define NG 64        // graphs
#define DIM 128      // feature dim (D == H == 128)
#define NCLS 10
#define SB 196       // scan blocks = ceil(NN/256)
#define NNP (SB*256) // padded node count (50176) so in/out halves are block-aligned
#define BLKP 256     // push blocks
#define NPB ((NN + BLKP - 1) / BLKP)   // nodes per push block = 196

typedef unsigned short ushort;
typedef __attribute__((ext_vector_type(8))) short short8;   // 8 bf16 (4 VGPRs)
typedef __attribute__((ext_vector_type(4))) float float4v;  // 4 fp32 acc

__device__ __forceinline__ ushort f2bf(float f) {
    unsigned u = __float_as_uint(f);
    u += 0x7fff + ((u >> 16) & 1);          // RNE
    return (ushort)(u >> 16);
}
__device__ __forceinline__ void acc8(float* a, uint4 v) {
    a[0] += __uint_as_float(v.x << 16); a[1] += __uint_as_float(v.x & 0xffff0000u);
    a[2] += __uint_as_float(v.y << 16); a[3] += __uint_as_float(v.y & 0xffff0000u);
    a[4] += __uint_as_float(v.z << 16); a[5] += __uint_as_float(v.z & 0xffff0000u);
    a[6] += __uint_as_float(v.w << 16); a[7] += __uint_as_float(v.w & 0xffff0000u);
}

// ---------------- init: zero [indeg|outdeg] (padded) + W1->bf16 frag order -
__global__ void k_init(int* __restrict__ cnt, const float* __restrict__ W1,
                       ushort* __restrict__ Wsw) {
    int b = blockIdx.x, t = threadIdx.x;
    if (b < 2 * SB) {
        cnt[b * 256 + t] = 0;             // covers 2*NNP ints exactly
    } else {
        int tid = (b - 2 * SB) * 256 + t; // 64 blocks -> 16384 entries
        int j = tid & 7;
        int lane = (tid >> 3) & 63;
        int frag = tid >> 9;              // nt*4+kc
        int nt = frag >> 2, kc = frag & 3;
        int k = kc * 32 + (lane >> 4) * 8 + j;
        int n = nt * 16 + (lane & 15);
        Wsw[tid] = f2bf(W1[k * DIM + n]);
    }
}

// ---------------- degree histograms: indeg by dst, outdeg by src ----------
__global__ void k_deg2(const int* __restrict__ row, const int* __restrict__ col,
                       int* __restrict__ cnt) {
    int e = (blockIdx.x * blockDim.x + threadIdx.x) * 2;
    if (e < NE) {
        int2 c = *(const int2*)(col + e);
        int2 r = *(const int2*)(row + e);
        atomicAdd(&cnt[c.x], 1);
        atomicAdd(&cnt[c.y], 1);
        atomicAdd(&cnt[NNP + r.x], 1);
        atomicAdd(&cnt[NNP + r.y], 1);
    }
}

// ---------------- per-block partial sums over [indeg|outdeg] + dinv --------
__global__ __launch_bounds__(256) void k_part(const int* __restrict__ cnt,
                                              int* __restrict__ partials,
                                              float* __restrict__ dinv) {
    __shared__ int sm[256];
    int b = blockIdx.x, t = threadIdx.x, i = b * 256 + t;
    int c = cnt[i];                       // pad entries are zero
    if (b < SB && i < NN) dinv[i] = rsqrtf(1.0f + (float)c);
    sm[t] = c;
    __syncthreads();
    for (int s = 128; s > 0; s >>= 1) {
        if (t < s) sm[t] += sm[t + s];
        __syncthreads();
    }
    if (t == 0) partials[b] = sm[0];
}

// 1-block exclusive scan of the 2*SB partials
__global__ __launch_bounds__(512) void k_scanp(int* partials) {
    __shared__ int sm[512];
    int t = threadIdx.x;
    int v = (t < 2 * SB) ? partials[t] : 0;
    sm[t] = v;
    __syncthreads();
    for (int off = 1; off < 512; off <<= 1) {
        int u = (t >= off) ? sm[t - off] : 0;
        __syncthreads();
        sm[t] += u;
        __syncthreads();
    }
    if (t < 2 * SB) partials[t] = sm[t] - v;   // exclusive prefix
}

// per-block exclusive scan + base -> offsets & cursors (cursors alias cnt)
__global__ __launch_bounds__(256) void k_off(int* cnt, const int* __restrict__ partials,
                                             int* __restrict__ offs, int* __restrict__ offs2) {
    __shared__ int sm[256];
    int b = blockIdx.x, t = threadIdx.x, i = b * 256 + t;
    int v = cnt[i];
    sm[t] = v;
    __syncthreads();
    for (int off = 1; off < 256; off <<= 1) {
        int u = (t >= off) ? sm[t - off] : 0;
        __syncthreads();
        sm[t] += u;
        __syncthreads();
    }
    int base = partials[b] + sm[t] - v;
    if (b < SB) {
        if (i < NN) { offs[i] = base; cnt[i] = base; }
        if (i == NN) offs[NN] = base;
    } else {
        int j = i - NNP;
        int base2 = base - NE;            // outdeg prefixes start after total indeg (=NE)
        if (j < NN) { offs2[j] = base2; cnt[i] = base2; }
        if (j == NN) offs2[NN] = base2;
    }
}

// ---------------- fill both structures ----------------
// csr (by dst): source node ids.  edata2 (by src): (graph_of_dst, dinv[dst]).
__global__ void k_fill(const int* __restrict__ row, const int* __restrict__ col,
                       const float* __restrict__ dinv, const int* __restrict__ batch,
                       int* __restrict__ cursor, int* __restrict__ csr,
                       int2* __restrict__ edata2) {
    int e = (blockIdx.x * blockDim.x + threadIdx.x) * 2;
    if (e < NE) {
        int2 r = *(const int2*)(row + e);
        int2 c = *(const int2*)(col + e);
        int p0 = atomicAdd(&cursor[c.x], 1); csr[p0] = r.x;
        int p1 = atomicAdd(&cursor[c.y], 1); csr[p1] = r.y;
        int q0 = atomicAdd(&cursor[NNP + r.x], 1);
        edata2[q0] = make_int2(batch[c.x], __float_as_int(dinv[c.x]));
        int q1 = atomicAdd(&cursor[NNP + r.y], 1);
        edata2[q1] = make_int2(batch[c.y], __float_as_int(dinv[c.y]));
    }
}

// ---------------- MFMA GEMM: Hs[n,c] = dinv[n] * sum_k x[n,k] W1[k,c] ------
__global__ __launch_bounds__(256) void k_gemm_mfma(const float* __restrict__ Ain,
                                                   const ushort* __restrict__ Wsw,
                                                   const float* __restrict__ dinv,
                                                   ushort* __restrict__ Hs) {
    const int t = threadIdx.x;
    const int wave = t >> 6, lane = t & 63;
    const int m = lane & 15, quad = lane >> 4;
    const int row0 = blockIdx.x * 64 + wave * 16;

    short8 bfrag[8][4];
#pragma unroll
    for (int nt = 0; nt < 8; ++nt)
#pragma unroll
        for (int kc = 0; kc < 4; ++kc)
            bfrag[nt][kc] = *(const short8*)(Wsw + ((nt * 4 + kc) * 64 + lane) * 8);

    float4v acc[8];
#pragma unroll
    for (int nt = 0; nt < 8; ++nt) acc[nt] = (float4v){0.f, 0.f, 0.f, 0.f};

    const int row = row0 + m;
    const int rclamp = row < NN ? row : NN - 1;

#pragma unroll
    for (int kc = 0; kc < 4; ++kc) {
        const float* ap = Ain + (size_t)rclamp * DIM + kc * 32 + quad * 8;
        float4 v0 = *(const float4*)ap;
        float4 v1 = *(const float4*)(ap + 4);
        union { short8 v; ushort u[8]; } tmp;
        tmp.u[0] = f2bf(v0.x); tmp.u[1] = f2bf(v0.y);
        tmp.u[2] = f2bf(v0.z); tmp.u[3] = f2bf(v0.w);
        tmp.u[4] = f2bf(v1.x); tmp.u[5] = f2bf(v1.y);
        tmp.u[6] = f2bf(v1.z); tmp.u[7] = f2bf(v1.w);
        short8 a = tmp.v;
#pragma unroll
        for (int nt = 0; nt < 8; ++nt)
            acc[nt] = __builtin_amdgcn_mfma_f32_16x16x32_bf16(a, bfrag[nt][kc], acc[nt], 0, 0, 0);
    }

    // C/D: col = nt*16 + (lane&15), row = row0 + quad*4 + reg
#pragma unroll
    for (int reg = 0; reg < 4; ++reg) {
        int r = row0 + quad * 4 + reg;
        if (r < NN) {
            float d = dinv[r];
#pragma unroll
            for (int nt = 0; nt < 8; ++nt)
                Hs[(size_t)r * DIM + nt * 16 + m] = f2bf(d * acc[nt][reg]);
        }
    }
}

// ---------------- CSR gather (bf16): A2 = relu(dinv[c]*(Hs[c]+sum Hs[r])+b1)
// 16 lanes/node, uint4 (8 bf16) per lane, up to 8 edge-rows in flight.
__global__ __launch_bounds__(256) void k_gather_bf(const int* __restrict__ offsets,
                                                   const int* __restrict__ csr,
                                                   const float* __restrict__ dinv,
                                                   const float* __restrict__ bias,
                                                   const ushort* __restrict__ Hs,
                                                   ushort* __restrict__ out) {
    int gt = blockIdx.x * blockDim.x + threadIdx.x;
    int node = gt >> 4, lane = gt & 15;
    if (node >= NN) return;
    int beg = offsets[node], end = offsets[node + 1];
    const size_t off = (size_t)lane * 8;

    float a[8] = {0.f, 0.f, 0.f, 0.f, 0.f, 0.f, 0.f, 0.f};
    acc8(a, *(const uint4*)(Hs + (size_t)node * DIM + off));   // self loop

    int e = beg;
    for (; e + 8 <= end; e += 8) {
        int r0 = csr[e], r1 = csr[e + 1], r2 = csr[e + 2], r3 = csr[e + 3];
        int r4 = csr[e + 4], r5 = csr[e + 5], r6 = csr[e + 6], r7 = csr[e + 7];
        uint4 v0 = *(const uint4*)(Hs + (size_t)r0 * DIM + off);
        uint4 v1 = *(const uint4*)(Hs + (size_t)r1 * DIM + off);
        uint4 v2 = *(const uint4*)(Hs + (size_t)r2 * DIM + off);
        uint4 v3 = *(const uint4*)(Hs + (size_t)r3 * DIM + off);
        uint4 v4 = *(const uint4*)(Hs + (size_t)r4 * DIM + off);
        uint4 v5 = *(const uint4*)(Hs + (size_t)r5 * DIM + off);
        uint4 v6 = *(const uint4*)(Hs + (size_t)r6 * DIM + off);
        uint4 v7 = *(const uint4*)(Hs + (size_t)r7 * DIM + off);
        acc8(a, v0); acc8(a, v1); acc8(a, v2); acc8(a, v3);
        acc8(a, v4); acc8(a, v5); acc8(a, v6); acc8(a, v7);
    }
    for (; e + 4 <= end; e += 4) {
        int r0 = csr[e], r1 = csr[e + 1], r2 = csr[e + 2], r3 = csr[e + 3];
        uint4 v0 = *(const uint4*)(Hs + (size_t)r0 * DIM + off);
        uint4 v1 = *(const uint4*)(Hs + (size_t)r1 * DIM + off);
        uint4 v2 = *(const uint4*)(Hs + (size_t)r2 * DIM + off);
        uint4 v3 = *(const uint4*)(Hs + (size_t)r3 * DIM + off);
        acc8(a, v0); acc8(a, v1); acc8(a, v2); acc8(a, v3);
    }
    for (; e < end; ++e)
        acc8(a, *(const uint4*)(Hs + (size_t)csr[e] * DIM + off));

    float d = dinv[node];
    float4 b0 = *(const float4*)(bias + off);
    float4 b1 = *(const float4*)(bias + off + 4);
    a[0] = fmaxf(fmaf(a[0], d, b0.x), 0.f); a[1] = fmaxf(fmaf(a[1], d, b0.y), 0.f);
    a[2] = fmaxf(fmaf(a[2], d, b0.z), 0.f); a[3] = fmaxf(fmaf(a[3], d, b0.w), 0.f);
    a[4] = fmaxf(fmaf(a[4], d, b1.x), 0.f); a[5] = fmaxf(fmaf(a[5], d, b1.y), 0.f);
    a[6] = fmaxf(fmaf(a[6], d, b1.z), 0.f); a[7] = fmaxf(fmaf(a[7], d, b1.w), 0.f);
    uint4 o;
    o.x = (unsigned)f2bf(a[0]) | ((unsigned)f2bf(a[1]) << 16);
    o.y = (unsigned)f2bf(a[2]) | ((unsigned)f2bf(a[3]) << 16);
    o.z = (unsigned)f2bf(a[4]) | ((unsigned)f2bf(a[5]) << 16);
    o.w = (unsigned)f2bf(a[6]) | ((unsigned)f2bf(a[7]) << 16);
    *(uint4*)(out + (size_t)node * DIM + off) = o;
}

// ---------------- push: P[g] = sum_n (dinv[n]^2 + sum_out w*dinv[n]) * A2[n]
// Streams A2 sequentially (each row read ONCE); accumulates into per-block
// LDS acc[NG][DIM] via LDS fp32 atomics (2-way banking = free). One wave per
// node at a time: 64 lanes cover 128 cols (2 each) -> no intra-wave aliasing.
__global__ __launch_bounds__(256) void k_pool_push(const int* __restrict__ offs2,
                                                   const int2* __restrict__ edata2,
                                                   const float* __restrict__ dinv,
                                                   const int* __restrict__ batch,
                                                   const ushort* __restrict__ A2,
                                                   float* __restrict__ partial) {
    __shared__ float acc[NG * DIM];   // 32 KB
    const int t = threadIdx.x;
    for (int i = t; i < NG * DIM; i += 256) acc[i] = 0.f;
    __syncthreads();

    const int wave = t >> 6, lane = t & 63;
    const int base = blockIdx.x * NPB;
    const int lim = min(base + NPB, NN);
    for (int n = base + wave; n < lim; n += 4) {
        unsigned rv = *(const unsigned*)(A2 + (size_t)n * DIM + lane * 2);
        float r0 = __uint_as_float(rv << 16);
        float r1 = __uint_as_float(rv & 0xffff0000u);
        float dn = dinv[n];
        int g0 = batch[n];
        float w0 = dn * dn;                       // self-loop weight
        atomicAdd(&acc[g0 * DIM + lane * 2], w0 * r0);
        atomicAdd(&acc[g0 * DIM + lane * 2 + 1], w0 * r1);
        int eb = offs2[n], ee = offs2[n + 1];
        for (int e = eb; e < ee; ++e) {
            int2 ed = edata2[e];
            float w = __int_as_float(ed.y) * dn;  // dinv[dst]*dinv[src]
            atomicAdd(&acc[ed.x * DIM + lane * 2], w * r0);
            atomicAdd(&acc[ed.x * DIM + lane * 2 + 1], w * r1);
        }
    }
    __syncthreads();
    float* dst = partial + (size_t)blockIdx.x * (NG * DIM);
    for (int i = t; i < NG * DIM; i += 256) dst[i] = acc[i];
}

// ---------------- reduce partials -> P[g]; pooled = P@W2/cnt + b2; logits --
__global__ __launch_bounds__(128) void k_final(const float* __restrict__ partial,
                                               const float* __restrict__ W2,
                                               const float* __restrict__ b2,
                                               const float* __restrict__ Wlin,
                                               const float* __restrict__ blin,
                                               const int* __restrict__ batch,
                                               float* __restrict__ out) {
    const int g = blockIdx.x;
    const int t = threadIdx.x;
    int start;
    { int a = 0, b = NN; while (a < b) { int m = (a + b) >> 1; if (batch[m] < g) a = m + 1; else b = m; } start = a; }
    int end;
    { int a = 0, b = NN; while (a < b) { int m = (a + b) >> 1; if (batch[m] < g + 1) a = m + 1; else b = m; } end = a; }
    const int cnt = end - start;

    float s = 0.f;
    for (int b = 0; b < BLKP; b += 4) {
        float s0 = partial[(size_t)(b + 0) * (NG * DIM) + g * DIM + t];
        float s1 = partial[(size_t)(b + 1) * (NG * DIM) + g * DIM + t];
        float s2 = partial[(size_t)(b + 2) * (NG * DIM) + g * DIM + t];
        float s3 = partial[(size_t)(b + 3) * (NG * DIM) + g * DIM + t];
        s += (s0 + s1) + (s2 + s3);
    }
    __shared__ float P[DIM];
    P[t] = s;
    __syncthreads();
    float acc = 0.f;
    for (int k = 0; k < DIM; ++k) acc += P[k] * W2[k * DIM + t];   // fp32 W2
    __shared__ float pooled[DIM];
    pooled[t] = (cnt > 0) ? (acc / (float)cnt + b2[t]) : 0.f;
    __syncthreads();
    if (t < NCLS) {
        float s2 = blin[t];
        for (int k = 0; k < DIM; ++k) s2 += pooled[k] * Wlin[k * NCLS + t];
        out[g * NCLS + t] = s2;
    }
}

extern "C" void kernel_launch(void* const* d_in, const int* in_sizes, int n_in,
                              void* d_out, int out_size, void* d_ws, size_t ws_size,
                              hipStream_t stream) {
    const float* x    = (const float*)d_in[0];
    const float* W1   = (const float*)d_in[1];
    const float* b1   = (const float*)d_in[2];
    const float* W2   = (const float*)d_in[3];
    const float* b2   = (const float*)d_in[4];
    const float* Wlin = (const float*)d_in[5];
    const float* blin = (const float*)d_in[6];
    const int* eidx   = (const int*)d_in[7];   // [2, E] flat: rows then cols
    const int* batch  = (const int*)d_in[8];
    float* out = (float*)d_out;

    char* ws = (char*)d_ws;
    float*  dinv     = (float*)(ws + 0);           // 200000 B
    int*    cnt      = (int*)(ws + 200000);        // 2*NNP ints = 401408 B (becomes cursors)
    int*    offs     = (int*)(ws + 601408);        // NN+1 ints
    int*    offs2    = (int*)(ws + 801424);        // NN+1 ints
    int*    csr      = (int*)(ws + 1001440);       // NE ints (by dst)
    int2*   edata2   = (int2*)(ws + 3401440);      // NE int2 (by src: g, dinv[dst])
    int*    partials = (int*)(ws + 8201440);       // 2*SB ints
    ushort* Wsw      = (ushort*)(ws + 8203488);    // 32768 B (W1 frags)
    ushort* bufA     = (ushort*)(ws + 8236256);    // 12.8 MB bf16 Hs1
    ushort* bufB     = (ushort*)(ws + 21036256);   // 12.8 MB bf16 A2
    float*  pushpt   = (float*)(ws + 33836256);    // BLKP*NG*DIM fp32 = 8 MB

    const int* erow = eidx;
    const int* ecol = eidx + NE;

    // ---- structure build: degrees, dinv, dual scan, dual fill, W1 prep ----
    k_init<<<2 * SB + 64, 256, 0, stream>>>(cnt, W1, Wsw);
    k_deg2<<<(NE / 2 + 255) / 256, 256, 0, stream>>>(erow, ecol, cnt);
    k_part<<<2 * SB, 256, 0, stream>>>(cnt, partials, dinv);
    k_scanp<<<1, 512, 0, stream>>>(partials);
    k_off<<<2 * SB, 256, 0, stream>>>(cnt, partials, offs, offs2);
    k_fill<<<(NE / 2 + 255) / 256, 256, 0, stream>>>(erow, ecol, dinv, batch, cnt, csr, edata2);

    const int gemm_grid = (NN + 63) / 64;            // 782
    const int node_grid = (NN * 16 + 255) / 256;     // 3125

    // layer 1: Hs1 = dinv*(x @ W1) ; A2 = relu(dinv*(self+nbrs) + b1)
    k_gemm_mfma<<<gemm_grid, 256, 0, stream>>>(x, Wsw, dinv, bufA);
    k_gather_bf<<<node_grid, 256, 0, stream>>>(offs, csr, dinv, b1, bufA, bufB);

    // layer 2 fully commuted: P[g] = weighted node sums of A2 (streaming push)
    k_pool_push<<<BLKP, 256, 0, stream>>>(offs2, edata2, dinv, batch, bufB, pushpt);

    // reduce + P@W2 (fp32) + /cnt + b2 + Wlin head
    k_final<<<NG, 128, 0, stream>>>(pushpt, W2, b2, Wlin, blin, batch, out);
}

// Round 9
// 259.970 us; speedup vs baseline: 2.7251x; 2.7251x over previous
//
#include <hip/hip_runtime.h>

#define NN 50000     // nodes
#define NE 600000    // directed edges (self loops handled separately)
#define NG 64        // graphs
#define DIM 128      // feature dim (D == H == 128)
#define NCLS 10
#define SB 196       // scan blocks = ceil(NN/256)
#define NNP 50176    // SB*256 = 224*224 (padded K for pool GEMM)
#define KBLK 224     // split-K blocks for pool GEMM
#define KCH 224      // K-chunk per block (KBLK*KCH == NNP)
#define E2B ((NE / 2 + 255) / 256)   // edge blocks, 2 edges/thread

typedef unsigned short ushort;
typedef __attribute__((ext_vector_type(8))) short short8;   // 8 bf16 (4 VGPRs)
typedef __attribute__((ext_vector_type(4))) float float4v;  // 4 fp32 acc

__device__ __forceinline__ ushort f2bf(float f) {
    unsigned u = __float_as_uint(f);
    u += 0x7fff + ((u >> 16) & 1);          // RNE
    return (ushort)(u >> 16);
}
__device__ __forceinline__ void acc8(float* a, uint4 v) {
    a[0] += __uint_as_float(v.x << 16); a[1] += __uint_as_float(v.x & 0xffff0000u);
    a[2] += __uint_as_float(v.y << 16); a[3] += __uint_as_float(v.y & 0xffff0000u);
    a[4] += __uint_as_float(v.z << 16); a[5] += __uint_as_float(v.z & 0xffff0000u);
    a[6] += __uint_as_float(v.w << 16); a[7] += __uint_as_float(v.w & 0xffff0000u);
}

// ---- init: zero cnt (SB blocks) + W1->bf16 frag order (64) + zero Wd (784)
__global__ void k_init(int* __restrict__ cnt, const float* __restrict__ W1,
                       ushort* __restrict__ Wsw, float* __restrict__ Wd) {
    int b = blockIdx.x, t = threadIdx.x;
    if (b < SB) {
        int i = b * 256 + t;
        if (i < NN) cnt[i] = 0;
    } else if (b < SB + 64) {
        int tid = (b - SB) * 256 + t;     // 16384 entries
        int j = tid & 7;
        int lane = (tid >> 3) & 63;
        int frag = tid >> 9;              // nt*4+kc
        int nt = frag >> 2, kc = frag & 3;
        int k = kc * 32 + (lane >> 4) * 8 + j;
        int n = nt * 16 + (lane & 15);
        Wsw[tid] = f2bf(W1[k * DIM + n]);
    } else {
        // zero Wd: 64*NNP floats = 802816 float4 = 784 blocks * 256 thr * 4
        float4* w4 = (float4*)Wd;
        int base = (b - SB - 64) * 256 + t;
#pragma unroll
        for (int i = 0; i < 4; ++i)
            w4[base + i * 200704] = make_float4(0.f, 0.f, 0.f, 0.f);
    }
}

// ---------------- in-degree histogram (by dst, 2 edges/thread) -------------
__global__ void k_deg_count(const int* __restrict__ col, int* __restrict__ cnt) {
    int e = (blockIdx.x * blockDim.x + threadIdx.x) * 2;
    if (e < NE) {
        int2 c = *(const int2*)(col + e);
        atomicAdd(&cnt[c.x], 1);
        atomicAdd(&cnt[c.y], 1);
    }
}

// -------- per-block partial sums + dinv + packed (batch, dinv) table -------
__global__ __launch_bounds__(256) void k_part(const int* __restrict__ cnt,
                                              int* __restrict__ partials,
                                              float* __restrict__ dinv,
                                              const int* __restrict__ batch,
                                              int2* __restrict__ pdat) {
    __shared__ int sm[256];
    int t = threadIdx.x, i = blockIdx.x * 256 + t;
    int c = (i < NN) ? cnt[i] : 0;
    if (i < NN) {
        float d = rsqrtf(1.0f + (float)c);   // self loop contributes 1
        dinv[i] = d;
        pdat[i] = make_int2(batch[i], __float_as_int(d));
    }
    sm[t] = c;
    __syncthreads();
    for (int s = 128; s > 0; s >>= 1) {
        if (t < s) sm[t] += sm[t + s];
        __syncthreads();
    }
    if (t == 0) partials[blockIdx.x] = sm[0];
}

// 1-block exclusive scan of the SB partials
__global__ __launch_bounds__(256) void k_scanp(int* partials) {
    __shared__ int sm[256];
    int t = threadIdx.x;
    int v = (t < SB) ? partials[t] : 0;
    sm[t] = v;
    __syncthreads();
    for (int off = 1; off < 256; off <<= 1) {
        int u = (t >= off) ? sm[t - off] : 0;
        __syncthreads();
        sm[t] += u;
        __syncthreads();
    }
    if (t < SB) partials[t] = sm[t] - v;   // exclusive prefix
}

// per-block exclusive scan + base -> offsets & cursor (cursor aliases cnt)
__global__ __launch_bounds__(256) void k_off(int* cnt, const int* __restrict__ partials,
                                             int* __restrict__ offsets) {
    __shared__ int sm[256];
    int t = threadIdx.x, i = blockIdx.x * 256 + t;
    int v = (i < NN) ? cnt[i] : 0;
    sm[t] = v;
    __syncthreads();
    for (int off = 1; off < 256; off <<= 1) {
        int u = (t >= off) ? sm[t - off] : 0;
        __syncthreads();
        sm[t] += u;
        __syncthreads();
    }
    int base = partials[blockIdx.x] + sm[t] - v;
    if (i < NN) { offsets[i] = base; cnt[i] = base; }
    if (i == NN) offsets[NN] = base;
}

// ---------------- CSR fill by dst (2 edges/thread): src ids only -----------
__global__ void k_csr_fill(const int* __restrict__ row, const int* __restrict__ col,
                           int* __restrict__ cursor, int* __restrict__ csr) {
    int e = (blockIdx.x * blockDim.x + threadIdx.x) * 2;
    if (e < NE) {
        int2 r = *(const int2*)(row + e);
        int2 c = *(const int2*)(col + e);
        int p0 = atomicAdd(&cursor[c.x], 1); csr[p0] = r.x;
        int p1 = atomicAdd(&cursor[c.y], 1); csr[p1] = r.y;
    }
}

// ------- dense pool-weight build: Wd[g][n] = sum over graph-g terms --------
// edge e (r->c): Wd[batch[c]][r] += dinv[c]*dinv[r];  self: Wd[batch[n]][n] += dinv[n]^2
__global__ void k_wbuild(const int* __restrict__ row, const int* __restrict__ col,
                         const int2* __restrict__ pdat, const float* __restrict__ dinv,
                         float* __restrict__ Wd) {
    int b = blockIdx.x, t = threadIdx.x;
    if (b < E2B) {
        int e = (b * 256 + t) * 2;
        if (e < NE) {
            int2 r = *(const int2*)(row + e);
            int2 c = *(const int2*)(col + e);
            int2 p0 = pdat[c.x];
            int2 p1 = pdat[c.y];
            atomicAdd(&Wd[(size_t)p0.x * NNP + r.x], __int_as_float(p0.y) * dinv[r.x]);
            atomicAdd(&Wd[(size_t)p1.x * NNP + r.y], __int_as_float(p1.y) * dinv[r.y]);
        }
    } else {
        int n = (b - E2B) * 256 + t;
        if (n < NN) {
            int2 p = pdat[n];
            float d = __int_as_float(p.y);
            atomicAdd(&Wd[(size_t)p.x * NNP + n], d * d);
        }
    }
}

// ---------------- MFMA GEMM: Hs[n,c] = dinv[n] * sum_k x[n,k] W1[k,c] ------
__global__ __launch_bounds__(256) void k_gemm_mfma(const float* __restrict__ Ain,
                                                   const ushort* __restrict__ Wsw,
                                                   const float* __restrict__ dinv,
                                                   ushort* __restrict__ Hs) {
    const int t = threadIdx.x;
    const int wave = t >> 6, lane = t & 63;
    const int m = lane & 15, quad = lane >> 4;
    const int row0 = blockIdx.x * 64 + wave * 16;

    short8 bfrag[8][4];
#pragma unroll
    for (int nt = 0; nt < 8; ++nt)
#pragma unroll
        for (int kc = 0; kc < 4; ++kc)
            bfrag[nt][kc] = *(const short8*)(Wsw + ((nt * 4 + kc) * 64 + lane) * 8);

    float4v acc[8];
#pragma unroll
    for (int nt = 0; nt < 8; ++nt) acc[nt] = (float4v){0.f, 0.f, 0.f, 0.f};

    const int row = row0 + m;
    const int rclamp = row < NN ? row : NN - 1;

#pragma unroll
    for (int kc = 0; kc < 4; ++kc) {
        const float* ap = Ain + (size_t)rclamp * DIM + kc * 32 + quad * 8;
        float4 v0 = *(const float4*)ap;
        float4 v1 = *(const float4*)(ap + 4);
        union { short8 v; ushort u[8]; } tmp;
        tmp.u[0] = f2bf(v0.x); tmp.u[1] = f2bf(v0.y);
        tmp.u[2] = f2bf(v0.z); tmp.u[3] = f2bf(v0.w);
        tmp.u[4] = f2bf(v1.x); tmp.u[5] = f2bf(v1.y);
        tmp.u[6] = f2bf(v1.z); tmp.u[7] = f2bf(v1.w);
        short8 a = tmp.v;
#pragma unroll
        for (int nt = 0; nt < 8; ++nt)
            acc[nt] = __builtin_amdgcn_mfma_f32_16x16x32_bf16(a, bfrag[nt][kc], acc[nt], 0, 0, 0);
    }

    // C/D: col = nt*16 + (lane&15), row = row0 + quad*4 + reg
#pragma unroll
    for (int reg = 0; reg < 4; ++reg) {
        int r = row0 + quad * 4 + reg;
        if (r < NN) {
            float d = dinv[r];
#pragma unroll
            for (int nt = 0; nt < 8; ++nt)
                Hs[(size_t)r * DIM + nt * 16 + m] = f2bf(d * acc[nt][reg]);
        }
    }
}

// ---------------- CSR gather (bf16): A2 = relu(dinv[c]*(Hs[c]+sum Hs[r])+b1)
// 16 lanes/node, uint4 (8 bf16) per lane, up to 8 edge-rows in flight.
__global__ __launch_bounds__(256) void k_gather_bf(const int* __restrict__ offsets,
                                                   const int* __restrict__ csr,
                                                   const float* __restrict__ dinv,
                                                   const float* __restrict__ bias,
                                                   const ushort* __restrict__ Hs,
                                                   ushort* __restrict__ out) {
    int gt = blockIdx.x * blockDim.x + threadIdx.x;
    int node = gt >> 4, lane = gt & 15;
    if (node >= NN) return;
    int beg = offsets[node], end = offsets[node + 1];
    const size_t off = (size_t)lane * 8;

    float a[8] = {0.f, 0.f, 0.f, 0.f, 0.f, 0.f, 0.f, 0.f};
    acc8(a, *(const uint4*)(Hs + (size_t)node * DIM + off));   // self loop

    int e = beg;
    for (; e + 8 <= end; e += 8) {
        int r0 = csr[e], r1 = csr[e + 1], r2 = csr[e + 2], r3 = csr[e + 3];
        int r4 = csr[e + 4], r5 = csr[e + 5], r6 = csr[e + 6], r7 = csr[e + 7];
        uint4 v0 = *(const uint4*)(Hs + (size_t)r0 * DIM + off);
        uint4 v1 = *(const uint4*)(Hs + (size_t)r1 * DIM + off);
        uint4 v2 = *(const uint4*)(Hs + (size_t)r2 * DIM + off);
        uint4 v3 = *(const uint4*)(Hs + (size_t)r3 * DIM + off);
        uint4 v4 = *(const uint4*)(Hs + (size_t)r4 * DIM + off);
        uint4 v5 = *(const uint4*)(Hs + (size_t)r5 * DIM + off);
        uint4 v6 = *(const uint4*)(Hs + (size_t)r6 * DIM + off);
        uint4 v7 = *(const uint4*)(Hs + (size_t)r7 * DIM + off);
        acc8(a, v0); acc8(a, v1); acc8(a, v2); acc8(a, v3);
        acc8(a, v4); acc8(a, v5); acc8(a, v6); acc8(a, v7);
    }
    for (; e + 4 <= end; e += 4) {
        int r0 = csr[e], r1 = csr[e + 1], r2 = csr[e + 2], r3 = csr[e + 3];
        uint4 v0 = *(const uint4*)(Hs + (size_t)r0 * DIM + off);
        uint4 v1 = *(const uint4*)(Hs + (size_t)r1 * DIM + off);
        uint4 v2 = *(const uint4*)(Hs + (size_t)r2 * DIM + off);
        uint4 v3 = *(const uint4*)(Hs + (size_t)r3 * DIM + off);
        acc8(a, v0); acc8(a, v1); acc8(a, v2); acc8(a, v3);
    }
    for (; e < end; ++e)
        acc8(a, *(const uint4*)(Hs + (size_t)csr[e] * DIM + off));

    float d = dinv[node];
    float4 b0 = *(const float4*)(bias + off);
    float4 b1 = *(const float4*)(bias + off + 4);
    a[0] = fmaxf(fmaf(a[0], d, b0.x), 0.f); a[1] = fmaxf(fmaf(a[1], d, b0.y), 0.f);
    a[2] = fmaxf(fmaf(a[2], d, b0.z), 0.f); a[3] = fmaxf(fmaf(a[3], d, b0.w), 0.f);
    a[4] = fmaxf(fmaf(a[4], d, b1.x), 0.f); a[5] = fmaxf(fmaf(a[5], d, b1.y), 0.f);
    a[6] = fmaxf(fmaf(a[6], d, b1.z), 0.f); a[7] = fmaxf(fmaf(a[7], d, b1.w), 0.f);
    uint4 o;
    o.x = (unsigned)f2bf(a[0]) | ((unsigned)f2bf(a[1]) << 16);
    o.y = (unsigned)f2bf(a[2]) | ((unsigned)f2bf(a[3]) << 16);
    o.z = (unsigned)f2bf(a[4]) | ((unsigned)f2bf(a[5]) << 16);
    o.w = (unsigned)f2bf(a[6]) | ((unsigned)f2bf(a[7]) << 16);
    *(uint4*)(out + (size_t)node * DIM + off) = o;
}

// ---------------- pool GEMM: P = Wd[64 x NNP] @ A2[NNP x 128], split-K -----
// Both operands streamed sequentially. Wd zero-padded for k >= NN.
// A-frag: A[m=lane&15][k=quad*8+j] = Wd[g][k]; B-frag: B[k][n=lane&15] = A2[k][n].
__global__ __launch_bounds__(256) void k_pool_gemm(const float* __restrict__ Wd,
                                                   const ushort* __restrict__ A2,
                                                   float* __restrict__ partial) {
    const int t = threadIdx.x;
    const int wave = t >> 6, lane = t & 63;
    const int m = lane & 15, quad = lane >> 4;
    const int g = wave * 16 + m;
    const size_t k0 = (size_t)blockIdx.x * KCH;

    float4v acc[8];
#pragma unroll
    for (int nt = 0; nt < 8; ++nt) acc[nt] = (float4v){0.f, 0.f, 0.f, 0.f};

    for (int ks = 0; ks < KCH; ks += 32) {
        const size_t kb = k0 + ks + quad * 8;
        const float* ap = Wd + (size_t)g * NNP + kb;
        float4 a0 = *(const float4*)ap;
        float4 a1 = *(const float4*)(ap + 4);
        union { short8 v; ushort u[8]; } af;
        af.u[0] = f2bf(a0.x); af.u[1] = f2bf(a0.y);
        af.u[2] = f2bf(a0.z); af.u[3] = f2bf(a0.w);
        af.u[4] = f2bf(a1.x); af.u[5] = f2bf(a1.y);
        af.u[6] = f2bf(a1.z); af.u[7] = f2bf(a1.w);

        const ushort* bbase = A2 + kb * DIM + m;
#pragma unroll
        for (int nt = 0; nt < 8; ++nt) {
            union { short8 v; ushort u[8]; } bf;
            const ushort* bp = bbase + nt * 16;
#pragma unroll
            for (int j = 0; j < 8; ++j) bf.u[j] = bp[(size_t)j * DIM];
            acc[nt] = __builtin_amdgcn_mfma_f32_16x16x32_bf16(af.v, bf.v, acc[nt], 0, 0, 0);
        }
    }

    float* dst = partial + (size_t)blockIdx.x * (NG * DIM);
#pragma unroll
    for (int reg = 0; reg < 4; ++reg) {
        int gg = wave * 16 + quad * 4 + reg;
#pragma unroll
        for (int nt = 0; nt < 8; ++nt)
            dst[gg * DIM + nt * 16 + m] = acc[nt][reg];
    }
}

// ------- reduce split-K partials -> P[g]; pooled = (P@W2)/cnt + b2; logits -
__global__ __launch_bounds__(128) void k_final(const float* __restrict__ partial,
                                               const float* __restrict__ W2,
                                               const float* __restrict__ b2,
                                               const float* __restrict__ Wlin,
                                               const float* __restrict__ blin,
                                               const int* __restrict__ batch,
                                               float* __restrict__ out) {
    const int g = blockIdx.x;
    const int t = threadIdx.x;
    int start;
    { int a = 0, b = NN; while (a < b) { int m = (a + b) >> 1; if (batch[m] < g) a = m + 1; else b = m; } start = a; }
    int end;
    { int a = 0, b = NN; while (a < b) { int m = (a + b) >> 1; if (batch[m] < g + 1) a = m + 1; else b = m; } end = a; }
    const int cnt = end - start;

    float s = 0.f;
    for (int b = 0; b < KBLK; b += 4) {
        float s0 = partial[(size_t)(b + 0) * (NG * DIM) + g * DIM + t];
        float s1 = partial[(size_t)(b + 1) * (NG * DIM) + g * DIM + t];
        float s2 = partial[(size_t)(b + 2) * (NG * DIM) + g * DIM + t];
        float s3 = partial[(size_t)(b + 3) * (NG * DIM) + g * DIM + t];
        s += (s0 + s1) + (s2 + s3);
    }
    __shared__ float P[DIM];
    P[t] = s;
    __syncthreads();
    float acc = 0.f;
    for (int k = 0; k < DIM; ++k) acc += P[k] * W2[k * DIM + t];   // fp32 W2
    __shared__ float pooled[DIM];
    pooled[t] = (cnt > 0) ? (acc / (float)cnt + b2[t]) : 0.f;
    __syncthreads();
    if (t < NCLS) {
        float s2 = blin[t];
        for (int k = 0; k < DIM; ++k) s2 += pooled[k] * Wlin[k * NCLS + t];
        out[g * NCLS + t] = s2;
    }
}

extern "C" void kernel_launch(void* const* d_in, const int* in_sizes, int n_in,
                              void* d_out, int out_size, void* d_ws, size_t ws_size,
                              hipStream_t stream) {
    const float* x    = (const float*)d_in[0];
    const float* W1   = (const float*)d_in[1];
    const float* b1   = (const float*)d_in[2];
    const float* W2   = (const float*)d_in[3];
    const float* b2   = (const float*)d_in[4];
    const float* Wlin = (const float*)d_in[5];
    const float* blin = (const float*)d_in[6];
    const int* eidx   = (const int*)d_in[7];   // [2, E] flat: rows then cols
    const int* batch  = (const int*)d_in[8];
    float* out = (float*)d_out;

    char* ws = (char*)d_ws;
    float*  dinv     = (float*)(ws + 0);           // 200000 B
    int*    cnt      = (int*)(ws + 200000);        // 200000 B (becomes cursor)
    int*    offs     = (int*)(ws + 400000);        // 200016 B (NN+1)
    int2*   pdat     = (int2*)(ws + 600016);       // 400000 B (batch, dinv)
    int*    csr      = (int*)(ws + 1000016);       // 2400000 B (by dst)
    int*    partials = (int*)(ws + 3400016);       // 1024 B
    ushort* Wsw      = (ushort*)(ws + 3401040);    // 32768 B (W1 frags)
    float*  Wd       = (float*)(ws + 3433808);     // 64*NNP fp32 = 12845056 B
    ushort* bufA     = (ushort*)(ws + 16278864);   // NN*DIM bf16 = 12800000 B (Hs1)
    ushort* bufB     = (ushort*)(ws + 29078864);   // NNP*DIM bf16 = 12845056 B (A2)
    float*  poolpt   = (float*)(ws + 41923920);    // KBLK*NG*DIM fp32 = 7340032 B

    const int* erow = eidx;
    const int* ecol = eidx + NE;

    // ---- structure build: zero+prep, degrees, dinv/pdat, scan, fills ----
    k_init<<<SB + 64 + 784, 256, 0, stream>>>(cnt, W1, Wsw, Wd);
    k_deg_count<<<E2B, 256, 0, stream>>>(ecol, cnt);
    k_part<<<SB, 256, 0, stream>>>(cnt, partials, dinv, batch, pdat);
    k_scanp<<<1, 256, 0, stream>>>(partials);
    k_off<<<SB, 256, 0, stream>>>(cnt, partials, offs);
    k_csr_fill<<<E2B, 256, 0, stream>>>(erow, ecol, cnt, csr);
    k_wbuild<<<E2B + SB, 256, 0, stream>>>(erow, ecol, pdat, dinv, Wd);

    const int gemm_grid = (NN + 63) / 64;            // 782
    const int node_grid = (NN * 16 + 255) / 256;     // 3125

    // layer 1: Hs1 = dinv*(x @ W1) ; A2 = relu(dinv*(self+nbrs) + b1)
    k_gemm_mfma<<<gemm_grid, 256, 0, stream>>>(x, Wsw, dinv, bufA);
    k_gather_bf<<<node_grid, 256, 0, stream>>>(offs, csr, dinv, b1, bufA, bufB);

    // layer 2 + pool, fully commuted: P = Wd @ A2 (streaming split-K MFMA)
    k_pool_gemm<<<KBLK, 256, 0, stream>>>(Wd, bufB, poolpt);

    // reduce + P@W2 (fp32) + /cnt + b2 + Wlin head
    k_final<<<NG, 128, 0, stream>>>(poolpt, W2, b2, Wlin, blin, batch, out);
}

// Round 10
// 225.115 us; speedup vs baseline: 3.1471x; 1.1548x over previous
//
#include <hip/hip_runtime.h>

#define NN 50000     // nodes
#define NE 600000    // directed edges (self loops handled separately)
#define NG 64        // graphs
#define DIM 128      // feature dim (D == H == 128)
#define NCLS 10
#define SB 196       // ceil(NN/256)
#define NNP 50176    // SB*256 = 224*224 (padded K for pool GEMM)
#define KBLK 224     // split-K blocks for pool GEMM
#define KCH 224      // K-chunk per block (KBLK*KCH == NNP)
#define CAP 64       // ELL row capacity (multinomial max deg ~33; 64 is safe)
#define E2B ((NE / 2 + 255) / 256)   // edge blocks, 2 edges/thread

typedef unsigned short ushort;
typedef __attribute__((ext_vector_type(8))) short short8;   // 8 bf16 (4 VGPRs)
typedef __attribute__((ext_vector_type(4))) float float4v;  // 4 fp32 acc

__device__ __forceinline__ ushort f2bf(float f) {
    unsigned u = __float_as_uint(f);
    u += 0x7fff + ((u >> 16) & 1);          // RNE
    return (ushort)(u >> 16);
}
__device__ __forceinline__ void acc8(float* a, uint4 v) {
    a[0] += __uint_as_float(v.x << 16); a[1] += __uint_as_float(v.x & 0xffff0000u);
    a[2] += __uint_as_float(v.y << 16); a[3] += __uint_as_float(v.y & 0xffff0000u);
    a[4] += __uint_as_float(v.z << 16); a[5] += __uint_as_float(v.z & 0xffff0000u);
    a[6] += __uint_as_float(v.w << 16); a[7] += __uint_as_float(v.w & 0xffff0000u);
}

// ---- init: zero cnt (SB blocks) + W1->bf16 frag order (64) + zero Wd (784)
__global__ void k_init(int* __restrict__ cnt, const float* __restrict__ W1,
                       ushort* __restrict__ Wsw, float* __restrict__ Wd) {
    int b = blockIdx.x, t = threadIdx.x;
    if (b < SB) {
        int i = b * 256 + t;
        if (i < NN) cnt[i] = 0;
    } else if (b < SB + 64) {
        int tid = (b - SB) * 256 + t;     // 16384 entries
        int j = tid & 7;
        int lane = (tid >> 3) & 63;
        int frag = tid >> 9;              // nt*4+kc
        int nt = frag >> 2, kc = frag & 3;
        int k = kc * 32 + (lane >> 4) * 8 + j;
        int n = nt * 16 + (lane & 15);
        Wsw[tid] = f2bf(W1[k * DIM + n]);
    } else {
        // zero Wd: 64*NNP floats = 802816 float4 = 784 blocks * 256 thr * 4
        float4* w4 = (float4*)Wd;
        int base = (b - SB - 64) * 256 + t;
#pragma unroll
        for (int i = 0; i < 4; ++i)
            w4[base + i * 200704] = make_float4(0.f, 0.f, 0.f, 0.f);
    }
}

// ------- single-pass ELL fill by dst (2 edges/thread); cnt ends as degree --
__global__ void k_fill(const int* __restrict__ row, const int* __restrict__ col,
                       int* __restrict__ cnt, int* __restrict__ ell) {
    int e = (blockIdx.x * blockDim.x + threadIdx.x) * 2;
    if (e < NE) {
        int2 r = *(const int2*)(row + e);
        int2 c = *(const int2*)(col + e);
        int p0 = atomicAdd(&cnt[c.x], 1);
        if (p0 < CAP) ell[c.x * CAP + p0] = r.x;
        int p1 = atomicAdd(&cnt[c.y], 1);
        if (p1 < CAP) ell[c.y * CAP + p1] = r.y;
    }
}

// ---------------- dinv + packed (batch, dinv) from final degrees -----------
__global__ void k_pd(const int* __restrict__ cnt, const int* __restrict__ batch,
                     float* __restrict__ dinv, int2* __restrict__ pdat) {
    int i = blockIdx.x * 256 + threadIdx.x;
    if (i < NN) {
        float d = rsqrtf(1.0f + (float)cnt[i]);   // self loop contributes 1
        dinv[i] = d;
        pdat[i] = make_int2(batch[i], __float_as_int(d));
    }
}

// ------- dense pool-weight build: Wd[g][n] = sum over graph-g terms --------
// edge e (r->c): Wd[batch[c]][r] += dinv[c]*dinv[r];  self: Wd[batch[n]][n] += dinv[n]^2
__global__ void k_wbuild(const int* __restrict__ row, const int* __restrict__ col,
                         const int2* __restrict__ pdat, const float* __restrict__ dinv,
                         float* __restrict__ Wd) {
    int b = blockIdx.x, t = threadIdx.x;
    if (b < E2B) {
        int e = (b * 256 + t) * 2;
        if (e < NE) {
            int2 r = *(const int2*)(row + e);
            int2 c = *(const int2*)(col + e);
            int2 p0 = pdat[c.x];
            int2 p1 = pdat[c.y];
            atomicAdd(&Wd[(size_t)p0.x * NNP + r.x], __int_as_float(p0.y) * dinv[r.x]);
            atomicAdd(&Wd[(size_t)p1.x * NNP + r.y], __int_as_float(p1.y) * dinv[r.y]);
        }
    } else {
        int n = (b - E2B) * 256 + t;
        if (n < NN) {
            int2 p = pdat[n];
            float d = __int_as_float(p.y);
            atomicAdd(&Wd[(size_t)p.x * NNP + n], d * d);
        }
    }
}

// ---------------- MFMA GEMM: Hs[n,c] = dinv[n] * sum_k x[n,k] W1[k,c] ------
__global__ __launch_bounds__(256) void k_gemm_mfma(const float* __restrict__ Ain,
                                                   const ushort* __restrict__ Wsw,
                                                   const float* __restrict__ dinv,
                                                   ushort* __restrict__ Hs) {
    const int t = threadIdx.x;
    const int wave = t >> 6, lane = t & 63;
    const int m = lane & 15, quad = lane >> 4;
    const int row0 = blockIdx.x * 64 + wave * 16;

    short8 bfrag[8][4];
#pragma unroll
    for (int nt = 0; nt < 8; ++nt)
#pragma unroll
        for (int kc = 0; kc < 4; ++kc)
            bfrag[nt][kc] = *(const short8*)(Wsw + ((nt * 4 + kc) * 64 + lane) * 8);

    float4v acc[8];
#pragma unroll
    for (int nt = 0; nt < 8; ++nt) acc[nt] = (float4v){0.f, 0.f, 0.f, 0.f};

    const int row = row0 + m;
    const int rclamp = row < NN ? row : NN - 1;

#pragma unroll
    for (int kc = 0; kc < 4; ++kc) {
        const float* ap = Ain + (size_t)rclamp * DIM + kc * 32 + quad * 8;
        float4 v0 = *(const float4*)ap;
        float4 v1 = *(const float4*)(ap + 4);
        union { short8 v; ushort u[8]; } tmp;
        tmp.u[0] = f2bf(v0.x); tmp.u[1] = f2bf(v0.y);
        tmp.u[2] = f2bf(v0.z); tmp.u[3] = f2bf(v0.w);
        tmp.u[4] = f2bf(v1.x); tmp.u[5] = f2bf(v1.y);
        tmp.u[6] = f2bf(v1.z); tmp.u[7] = f2bf(v1.w);
        short8 a = tmp.v;
#pragma unroll
        for (int nt = 0; nt < 8; ++nt)
            acc[nt] = __builtin_amdgcn_mfma_f32_16x16x32_bf16(a, bfrag[nt][kc], acc[nt], 0, 0, 0);
    }

    // C/D: col = nt*16 + (lane&15), row = row0 + quad*4 + reg
#pragma unroll
    for (int reg = 0; reg < 4; ++reg) {
        int r = row0 + quad * 4 + reg;
        if (r < NN) {
            float d = dinv[r];
#pragma unroll
            for (int nt = 0; nt < 8; ++nt)
                Hs[(size_t)r * DIM + nt * 16 + m] = f2bf(d * acc[nt][reg]);
        }
    }
}

// -------- ELL gather (bf16): A2 = relu(dinv[c]*(Hs[c]+sum Hs[r])+b1) -------
// 16 lanes/node, uint4 (8 bf16) per lane, up to 8 edge-rows in flight.
__global__ __launch_bounds__(256) void k_gather_ell(const int* __restrict__ ell,
                                                    const int* __restrict__ deg,
                                                    const float* __restrict__ dinv,
                                                    const float* __restrict__ bias,
                                                    const ushort* __restrict__ Hs,
                                                    ushort* __restrict__ out) {
    int gt = blockIdx.x * blockDim.x + threadIdx.x;
    int node = gt >> 4, lane = gt & 15;
    if (node >= NN) return;
    const int* rowp = ell + node * CAP;
    int end = min(deg[node], CAP);
    const size_t off = (size_t)lane * 8;

    float a[8] = {0.f, 0.f, 0.f, 0.f, 0.f, 0.f, 0.f, 0.f};
    acc8(a, *(const uint4*)(Hs + (size_t)node * DIM + off));   // self loop

    int e = 0;
    for (; e + 8 <= end; e += 8) {
        int r0 = rowp[e], r1 = rowp[e + 1], r2 = rowp[e + 2], r3 = rowp[e + 3];
        int r4 = rowp[e + 4], r5 = rowp[e + 5], r6 = rowp[e + 6], r7 = rowp[e + 7];
        uint4 v0 = *(const uint4*)(Hs + (size_t)r0 * DIM + off);
        uint4 v1 = *(const uint4*)(Hs + (size_t)r1 * DIM + off);
        uint4 v2 = *(const uint4*)(Hs + (size_t)r2 * DIM + off);
        uint4 v3 = *(const uint4*)(Hs + (size_t)r3 * DIM + off);
        uint4 v4 = *(const uint4*)(Hs + (size_t)r4 * DIM + off);
        uint4 v5 = *(const uint4*)(Hs + (size_t)r5 * DIM + off);
        uint4 v6 = *(const uint4*)(Hs + (size_t)r6 * DIM + off);
        uint4 v7 = *(const uint4*)(Hs + (size_t)r7 * DIM + off);
        acc8(a, v0); acc8(a, v1); acc8(a, v2); acc8(a, v3);
        acc8(a, v4); acc8(a, v5); acc8(a, v6); acc8(a, v7);
    }
    for (; e + 4 <= end; e += 4) {
        int r0 = rowp[e], r1 = rowp[e + 1], r2 = rowp[e + 2], r3 = rowp[e + 3];
        uint4 v0 = *(const uint4*)(Hs + (size_t)r0 * DIM + off);
        uint4 v1 = *(const uint4*)(Hs + (size_t)r1 * DIM + off);
        uint4 v2 = *(const uint4*)(Hs + (size_t)r2 * DIM + off);
        uint4 v3 = *(const uint4*)(Hs + (size_t)r3 * DIM + off);
        acc8(a, v0); acc8(a, v1); acc8(a, v2); acc8(a, v3);
    }
    for (; e < end; ++e)
        acc8(a, *(const uint4*)(Hs + (size_t)rowp[e] * DIM + off));

    float d = dinv[node];
    float4 b0 = *(const float4*)(bias + off);
    float4 b1 = *(const float4*)(bias + off + 4);
    a[0] = fmaxf(fmaf(a[0], d, b0.x), 0.f); a[1] = fmaxf(fmaf(a[1], d, b0.y), 0.f);
    a[2] = fmaxf(fmaf(a[2], d, b0.z), 0.f); a[3] = fmaxf(fmaf(a[3], d, b0.w), 0.f);
    a[4] = fmaxf(fmaf(a[4], d, b1.x), 0.f); a[5] = fmaxf(fmaf(a[5], d, b1.y), 0.f);
    a[6] = fmaxf(fmaf(a[6], d, b1.z), 0.f); a[7] = fmaxf(fmaf(a[7], d, b1.w), 0.f);
    uint4 o;
    o.x = (unsigned)f2bf(a[0]) | ((unsigned)f2bf(a[1]) << 16);
    o.y = (unsigned)f2bf(a[2]) | ((unsigned)f2bf(a[3]) << 16);
    o.z = (unsigned)f2bf(a[4]) | ((unsigned)f2bf(a[5]) << 16);
    o.w = (unsigned)f2bf(a[6]) | ((unsigned)f2bf(a[7]) << 16);
    *(uint4*)(out + (size_t)node * DIM + off) = o;
}

// ---------------- pool GEMM: P = Wd[64 x NNP] @ A2[NNP x 128], split-K -----
// Both operands streamed sequentially. Wd zero-padded for k >= NN.
__global__ __launch_bounds__(256) void k_pool_gemm(const float* __restrict__ Wd,
                                                   const ushort* __restrict__ A2,
                                                   float* __restrict__ partial) {
    const int t = threadIdx.x;
    const int wave = t >> 6, lane = t & 63;
    const int m = lane & 15, quad = lane >> 4;
    const int g = wave * 16 + m;
    const size_t k0 = (size_t)blockIdx.x * KCH;

    float4v acc[8];
#pragma unroll
    for (int nt = 0; nt < 8; ++nt) acc[nt] = (float4v){0.f, 0.f, 0.f, 0.f};

    for (int ks = 0; ks < KCH; ks += 32) {
        const size_t kb = k0 + ks + quad * 8;
        const float* ap = Wd + (size_t)g * NNP + kb;
        float4 a0 = *(const float4*)ap;
        float4 a1 = *(const float4*)(ap + 4);
        union { short8 v; ushort u[8]; } af;
        af.u[0] = f2bf(a0.x); af.u[1] = f2bf(a0.y);
        af.u[2] = f2bf(a0.z); af.u[3] = f2bf(a0.w);
        af.u[4] = f2bf(a1.x); af.u[5] = f2bf(a1.y);
        af.u[6] = f2bf(a1.z); af.u[7] = f2bf(a1.w);

        const ushort* bbase = A2 + kb * DIM + m;
#pragma unroll
        for (int nt = 0; nt < 8; ++nt) {
            union { short8 v; ushort u[8]; } bf;
            const ushort* bp = bbase + nt * 16;
#pragma unroll
            for (int j = 0; j < 8; ++j) bf.u[j] = bp[(size_t)j * DIM];
            acc[nt] = __builtin_amdgcn_mfma_f32_16x16x32_bf16(af.v, bf.v, acc[nt], 0, 0, 0);
        }
    }

    float* dst = partial + (size_t)blockIdx.x * (NG * DIM);
#pragma unroll
    for (int reg = 0; reg < 4; ++reg) {
        int gg = wave * 16 + quad * 4 + reg;
#pragma unroll
        for (int nt = 0; nt < 8; ++nt)
            dst[gg * DIM + nt * 16 + m] = acc[nt][reg];
    }
}

// ------- reduce split-K partials -> P[g]; pooled = (P@W2)/cnt + b2; logits -
__global__ __launch_bounds__(128) void k_final(const float* __restrict__ partial,
                                               const float* __restrict__ W2,
                                               const float* __restrict__ b2,
                                               const float* __restrict__ Wlin,
                                               const float* __restrict__ blin,
                                               const int* __restrict__ batch,
                                               float* __restrict__ out) {
    const int g = blockIdx.x;
    const int t = threadIdx.x;
    int start;
    { int a = 0, b = NN; while (a < b) { int m = (a + b) >> 1; if (batch[m] < g) a = m + 1; else b = m; } start = a; }
    int end;
    { int a = 0, b = NN; while (a < b) { int m = (a + b) >> 1; if (batch[m] < g + 1) a = m + 1; else b = m; } end = a; }
    const int cnt = end - start;

    float s = 0.f;
    for (int b = 0; b < KBLK; b += 4) {
        float s0 = partial[(size_t)(b + 0) * (NG * DIM) + g * DIM + t];
        float s1 = partial[(size_t)(b + 1) * (NG * DIM) + g * DIM + t];
        float s2 = partial[(size_t)(b + 2) * (NG * DIM) + g * DIM + t];
        float s3 = partial[(size_t)(b + 3) * (NG * DIM) + g * DIM + t];
        s += (s0 + s1) + (s2 + s3);
    }
    __shared__ float P[DIM];
    P[t] = s;
    __syncthreads();
    float acc = 0.f;
    for (int k = 0; k < DIM; ++k) acc += P[k] * W2[k * DIM + t];   // fp32 W2
    __shared__ float pooled[DIM];
    pooled[t] = (cnt > 0) ? (acc / (float)cnt + b2[t]) : 0.f;
    __syncthreads();
    if (t < NCLS) {
        float s2 = blin[t];
        for (int k = 0; k < DIM; ++k) s2 += pooled[k] * Wlin[k * NCLS + t];
        out[g * NCLS + t] = s2;
    }
}

extern "C" void kernel_launch(void* const* d_in, const int* in_sizes, int n_in,
                              void* d_out, int out_size, void* d_ws, size_t ws_size,
                              hipStream_t stream) {
    const float* x    = (const float*)d_in[0];
    const float* W1   = (const float*)d_in[1];
    const float* b1   = (const float*)d_in[2];
    const float* W2   = (const float*)d_in[3];
    const float* b2   = (const float*)d_in[4];
    const float* Wlin = (const float*)d_in[5];
    const float* blin = (const float*)d_in[6];
    const int* eidx   = (const int*)d_in[7];   // [2, E] flat: rows then cols
    const int* batch  = (const int*)d_in[8];
    float* out = (float*)d_out;

    char* ws = (char*)d_ws;
    int*    cnt   = (int*)(ws + 0);             // NN ints (zeroed; ends as degree)
    float*  dinv  = (float*)(ws + 200000);      // NN floats
    int2*   pdat  = (int2*)(ws + 400000);       // NN int2 (batch, dinv)
    int*    ell   = (int*)(ws + 800000);        // NN*CAP ints = 12.8 MB
    ushort* Wsw   = (ushort*)(ws + 13600000);   // 32768 B (W1 frags)
    float*  Wd    = (float*)(ws + 13632768);    // 64*NNP fp32 = 12845056 B
    ushort* bufA  = (ushort*)(ws + 26477824);   // NN*DIM bf16 (Hs1)
    ushort* bufB  = (ushort*)(ws + 39277824);   // NNP*DIM bf16 (A2; tail x Wd=0)
    float*  poolpt= (float*)(ws + 52122880);    // KBLK*NG*DIM fp32 = 7.3 MB

    const int* erow = eidx;
    const int* ecol = eidx + NE;

    // ---- structure build: zero+Wprep, single-pass ELL fill, dinv/pdat ----
    k_init<<<SB + 64 + 784, 256, 0, stream>>>(cnt, W1, Wsw, Wd);
    k_fill<<<E2B, 256, 0, stream>>>(erow, ecol, cnt, ell);
    k_pd<<<SB, 256, 0, stream>>>(cnt, batch, dinv, pdat);

    const int gemm_grid = (NN + 63) / 64;            // 782
    const int node_grid = (NN * 16 + 255) / 256;     // 3125

    // layer 1: Hs1 = dinv*(x @ W1) ; A2 = relu(dinv*(self+nbrs) + b1)
    k_gemm_mfma<<<gemm_grid, 256, 0, stream>>>(x, Wsw, dinv, bufA);
    k_gather_ell<<<node_grid, 256, 0, stream>>>(ell, cnt, dinv, b1, bufA, bufB);

    // layer 2 + pool, fully commuted: P = Wd @ A2 (streaming split-K MFMA)
    k_wbuild<<<E2B + SB, 256, 0, stream>>>(erow, ecol, pdat, dinv, Wd);
    k_pool_gemm<<<KBLK, 256, 0, stream>>>(Wd, bufB, poolpt);

    // reduce + P@W2 (fp32) + /cnt + b2 + Wlin head
    k_final<<<NG, 128, 0, stream>>>(poolpt, W2, b2, Wlin, blin, batch, out);
}

// Round 11
// 210.442 us; speedup vs baseline: 3.3665x; 1.0697x over previous
//
#include <hip/hip_runtime.h>

#define NN 50000     // nodes
#define NE 600000    // directed edges (self loops handled separately)
#define NG 64        // graphs
#define DIM 128      // feature dim (D == H == 128)
#define NCLS 10
#define SB 196       // ceil(NN/256)
#define NNP 50176    // SB*256 = 224*224 (padded K for pool GEMM)
#define KBLK 224     // split-K blocks for pool GEMM
#define KCH 224      // K-chunk per block (KBLK*KCH == NNP)
#define CAP 64       // ELL row capacity (multinomial max deg ~33; 64 is safe)
#define E2B ((NE / 2 + 255) / 256)   // edge blocks, 2 edges/thread

typedef unsigned short ushort;
typedef unsigned char uchar;
typedef __attribute__((ext_vector_type(8))) short short8;   // 8 bf16 (4 VGPRs)
typedef __attribute__((ext_vector_type(4))) float float4v;  // 4 fp32 acc
typedef __attribute__((ext_vector_type(2))) float float2v;

__device__ __forceinline__ ushort f2bf(float f) {
    unsigned u = __float_as_uint(f);
    u += 0x7fff + ((u >> 16) & 1);          // RNE
    return (ushort)(u >> 16);
}
// fp8 e4m3 (OCP) encode via HW cvt (RNE, satfinite)
__device__ __forceinline__ uchar f2fp8(float f) {
    int p = __builtin_amdgcn_cvt_pk_fp8_f32(f, f, 0, false);
    return (uchar)(p & 0xff);
}
// decode 8 fp8 (uint2) -> accumulate into a[0..7]
__device__ __forceinline__ void accfp8(float* a, uint2 v) {
    float2v p0 = __builtin_amdgcn_cvt_pk_f32_fp8(v.x, false);
    float2v p1 = __builtin_amdgcn_cvt_pk_f32_fp8(v.x, true);
    float2v p2 = __builtin_amdgcn_cvt_pk_f32_fp8(v.y, false);
    float2v p3 = __builtin_amdgcn_cvt_pk_f32_fp8(v.y, true);
    a[0] += p0[0]; a[1] += p0[1]; a[2] += p1[0]; a[3] += p1[1];
    a[4] += p2[0]; a[5] += p2[1]; a[6] += p3[0]; a[7] += p3[1];
}

// ---- init: zero cnt (SB blocks) + W1->bf16 frag order (64) + zero Wd (784)
__global__ void k_init(int* __restrict__ cnt, const float* __restrict__ W1,
                       ushort* __restrict__ Wsw, float* __restrict__ Wd) {
    int b = blockIdx.x, t = threadIdx.x;
    if (b < SB) {
        int i = b * 256 + t;
        if (i < NN) cnt[i] = 0;
    } else if (b < SB + 64) {
        int tid = (b - SB) * 256 + t;     // 16384 entries
        int j = tid & 7;
        int lane = (tid >> 3) & 63;
        int frag = tid >> 9;              // nt*4+kc
        int nt = frag >> 2, kc = frag & 3;
        int k = kc * 32 + (lane >> 4) * 8 + j;
        int n = nt * 16 + (lane & 15);
        Wsw[tid] = f2bf(W1[k * DIM + n]);
    } else {
        // zero Wd: 64*NNP floats = 802816 float4 = 784 blocks * 256 thr * 4
        float4* w4 = (float4*)Wd;
        int base = (b - SB - 64) * 256 + t;
#pragma unroll
        for (int i = 0; i < 4; ++i)
            w4[base + i * 200704] = make_float4(0.f, 0.f, 0.f, 0.f);
    }
}

// ------- single-pass ELL fill by dst (2 edges/thread); cnt ends as degree --
__global__ void k_fill(const int* __restrict__ row, const int* __restrict__ col,
                       int* __restrict__ cnt, int* __restrict__ ell) {
    int e = (blockIdx.x * blockDim.x + threadIdx.x) * 2;
    if (e < NE) {
        int2 r = *(const int2*)(row + e);
        int2 c = *(const int2*)(col + e);
        int p0 = atomicAdd(&cnt[c.x], 1);
        if (p0 < CAP) ell[c.x * CAP + p0] = r.x;
        int p1 = atomicAdd(&cnt[c.y], 1);
        if (p1 < CAP) ell[c.y * CAP + p1] = r.y;
    }
}

// ---------------- MFMA GEMM: Hs[n,c] = fp8(dinv[n] * sum_k x[n,k] W1[k,c]) -
// Also materializes dinv[n] = rsqrt(1+deg[n]) for wbuild/gather reuse.
__global__ __launch_bounds__(256) void k_gemm_mfma(const float* __restrict__ Ain,
                                                   const ushort* __restrict__ Wsw,
                                                   const int* __restrict__ cnt,
                                                   uchar* __restrict__ Hs,
                                                   float* __restrict__ dinv) {
    const int t = threadIdx.x;
    const int wave = t >> 6, lane = t & 63;
    const int m = lane & 15, quad = lane >> 4;
    const int row0 = blockIdx.x * 64 + wave * 16;

    short8 bfrag[8][4];
#pragma unroll
    for (int nt = 0; nt < 8; ++nt)
#pragma unroll
        for (int kc = 0; kc < 4; ++kc)
            bfrag[nt][kc] = *(const short8*)(Wsw + ((nt * 4 + kc) * 64 + lane) * 8);

    float4v acc[8];
#pragma unroll
    for (int nt = 0; nt < 8; ++nt) acc[nt] = (float4v){0.f, 0.f, 0.f, 0.f};

    const int row = row0 + m;
    const int rclamp = row < NN ? row : NN - 1;

#pragma unroll
    for (int kc = 0; kc < 4; ++kc) {
        const float* ap = Ain + (size_t)rclamp * DIM + kc * 32 + quad * 8;
        float4 v0 = *(const float4*)ap;
        float4 v1 = *(const float4*)(ap + 4);
        union { short8 v; ushort u[8]; } tmp;
        tmp.u[0] = f2bf(v0.x); tmp.u[1] = f2bf(v0.y);
        tmp.u[2] = f2bf(v0.z); tmp.u[3] = f2bf(v0.w);
        tmp.u[4] = f2bf(v1.x); tmp.u[5] = f2bf(v1.y);
        tmp.u[6] = f2bf(v1.z); tmp.u[7] = f2bf(v1.w);
        short8 a = tmp.v;
#pragma unroll
        for (int nt = 0; nt < 8; ++nt)
            acc[nt] = __builtin_amdgcn_mfma_f32_16x16x32_bf16(a, bfrag[nt][kc], acc[nt], 0, 0, 0);
    }

    // C/D: col = nt*16 + (lane&15), row = row0 + quad*4 + reg
#pragma unroll
    for (int reg = 0; reg < 4; ++reg) {
        int r = row0 + quad * 4 + reg;
        if (r < NN) {
            float d = rsqrtf(1.0f + (float)cnt[r]);
            if (m == 0) dinv[r] = d;
#pragma unroll
            for (int nt = 0; nt < 8; ++nt)
                Hs[(size_t)r * DIM + nt * 16 + m] = f2fp8(d * acc[nt][reg]);
        }
    }
}

// -------- ELL gather (fp8 in): A2 = bf16(relu(dinv[c]*(Hs[c]+sum Hs[r])+b1))
// 16 lanes/node, uint2 (8 fp8) per lane, up to 8 edge-rows in flight.
__global__ __launch_bounds__(256) void k_gather_ell(const int* __restrict__ ell,
                                                    const int* __restrict__ deg,
                                                    const float* __restrict__ bias,
                                                    const uchar* __restrict__ Hs,
                                                    ushort* __restrict__ out) {
    int gt = blockIdx.x * blockDim.x + threadIdx.x;
    int node = gt >> 4, lane = gt & 15;
    if (node >= NN) return;
    const int* rowp = ell + node * CAP;
    int end = min(deg[node], CAP);
    const size_t off = (size_t)lane * 8;

    float a[8] = {0.f, 0.f, 0.f, 0.f, 0.f, 0.f, 0.f, 0.f};
    accfp8(a, *(const uint2*)(Hs + (size_t)node * DIM + off));   // self loop

    int e = 0;
    for (; e + 8 <= end; e += 8) {
        int r0 = rowp[e], r1 = rowp[e + 1], r2 = rowp[e + 2], r3 = rowp[e + 3];
        int r4 = rowp[e + 4], r5 = rowp[e + 5], r6 = rowp[e + 6], r7 = rowp[e + 7];
        uint2 v0 = *(const uint2*)(Hs + (size_t)r0 * DIM + off);
        uint2 v1 = *(const uint2*)(Hs + (size_t)r1 * DIM + off);
        uint2 v2 = *(const uint2*)(Hs + (size_t)r2 * DIM + off);
        uint2 v3 = *(const uint2*)(Hs + (size_t)r3 * DIM + off);
        uint2 v4 = *(const uint2*)(Hs + (size_t)r4 * DIM + off);
        uint2 v5 = *(const uint2*)(Hs + (size_t)r5 * DIM + off);
        uint2 v6 = *(const uint2*)(Hs + (size_t)r6 * DIM + off);
        uint2 v7 = *(const uint2*)(Hs + (size_t)r7 * DIM + off);
        accfp8(a, v0); accfp8(a, v1); accfp8(a, v2); accfp8(a, v3);
        accfp8(a, v4); accfp8(a, v5); accfp8(a, v6); accfp8(a, v7);
    }
    for (; e + 4 <= end; e += 4) {
        int r0 = rowp[e], r1 = rowp[e + 1], r2 = rowp[e + 2], r3 = rowp[e + 3];
        uint2 v0 = *(const uint2*)(Hs + (size_t)r0 * DIM + off);
        uint2 v1 = *(const uint2*)(Hs + (size_t)r1 * DIM + off);
        uint2 v2 = *(const uint2*)(Hs + (size_t)r2 * DIM + off);
        uint2 v3 = *(const uint2*)(Hs + (size_t)r3 * DIM + off);
        accfp8(a, v0); accfp8(a, v1); accfp8(a, v2); accfp8(a, v3);
    }
    for (; e < end; ++e)
        accfp8(a, *(const uint2*)(Hs + (size_t)rowp[e] * DIM + off));

    float d = rsqrtf(1.0f + (float)end);
    float4 b0 = *(const float4*)(bias + off);
    float4 b1 = *(const float4*)(bias + off + 4);
    a[0] = fmaxf(fmaf(a[0], d, b0.x), 0.f); a[1] = fmaxf(fmaf(a[1], d, b0.y), 0.f);
    a[2] = fmaxf(fmaf(a[2], d, b0.z), 0.f); a[3] = fmaxf(fmaf(a[3], d, b0.w), 0.f);
    a[4] = fmaxf(fmaf(a[4], d, b1.x), 0.f); a[5] = fmaxf(fmaf(a[5], d, b1.y), 0.f);
    a[6] = fmaxf(fmaf(a[6], d, b1.z), 0.f); a[7] = fmaxf(fmaf(a[7], d, b1.w), 0.f);
    uint4 o;
    o.x = (unsigned)f2bf(a[0]) | ((unsigned)f2bf(a[1]) << 16);
    o.y = (unsigned)f2bf(a[2]) | ((unsigned)f2bf(a[3]) << 16);
    o.z = (unsigned)f2bf(a[4]) | ((unsigned)f2bf(a[5]) << 16);
    o.w = (unsigned)f2bf(a[6]) | ((unsigned)f2bf(a[7]) << 16);
    *(uint4*)(out + (size_t)node * DIM + off) = o;
}

// ------- dense pool-weight build: Wd[g][n] = sum over graph-g terms --------
// edge e (r->c): Wd[batch[c]][r] += dinv[c]*dinv[r];  self: Wd[batch[n]][n] += dinv[n]^2
__global__ void k_wbuild(const int* __restrict__ row, const int* __restrict__ col,
                         const float* __restrict__ dinv, const int* __restrict__ batch,
                         float* __restrict__ Wd) {
    int b = blockIdx.x, t = threadIdx.x;
    if (b < E2B) {
        int e = (b * 256 + t) * 2;
        if (e < NE) {
            int2 r = *(const int2*)(row + e);
            int2 c = *(const int2*)(col + e);
            atomicAdd(&Wd[(size_t)batch[c.x] * NNP + r.x], dinv[c.x] * dinv[r.x]);
            atomicAdd(&Wd[(size_t)batch[c.y] * NNP + r.y], dinv[c.y] * dinv[r.y]);
        }
    } else {
        int n = (b - E2B) * 256 + t;
        if (n < NN) {
            float d = dinv[n];
            atomicAdd(&Wd[(size_t)batch[n] * NNP + n], d * d);
        }
    }
}

// ---------------- pool GEMM: P = Wd[64 x NNP] @ A2[NNP x 128], split-K -----
// Both operands streamed sequentially. Wd zero-padded for k >= NN.
__global__ __launch_bounds__(256) void k_pool_gemm(const float* __restrict__ Wd,
                                                   const ushort* __restrict__ A2,
                                                   float* __restrict__ partial) {
    const int t = threadIdx.x;
    const int wave = t >> 6, lane = t & 63;
    const int m = lane & 15, quad = lane >> 4;
    const int g = wave * 16 + m;
    const size_t k0 = (size_t)blockIdx.x * KCH;

    float4v acc[8];
#pragma unroll
    for (int nt = 0; nt < 8; ++nt) acc[nt] = (float4v){0.f, 0.f, 0.f, 0.f};

    for (int ks = 0; ks < KCH; ks += 32) {
        const size_t kb = k0 + ks + quad * 8;
        const float* ap = Wd + (size_t)g * NNP + kb;
        float4 a0 = *(const float4*)ap;
        float4 a1 = *(const float4*)(ap + 4);
        union { short8 v; ushort u[8]; } af;
        af.u[0] = f2bf(a0.x); af.u[1] = f2bf(a0.y);
        af.u[2] = f2bf(a0.z); af.u[3] = f2bf(a0.w);
        af.u[4] = f2bf(a1.x); af.u[5] = f2bf(a1.y);
        af.u[6] = f2bf(a1.z); af.u[7] = f2bf(a1.w);

        const ushort* bbase = A2 + kb * DIM + m;
#pragma unroll
        for (int nt = 0; nt < 8; ++nt) {
            union { short8 v; ushort u[8]; } bf;
            const ushort* bp = bbase + nt * 16;
#pragma unroll
            for (int j = 0; j < 8; ++j) bf.u[j] = bp[(size_t)j * DIM];
            acc[nt] = __builtin_amdgcn_mfma_f32_16x16x32_bf16(af.v, bf.v, acc[nt], 0, 0, 0);
        }
    }

    float* dst = partial + (size_t)blockIdx.x * (NG * DIM);
#pragma unroll
    for (int reg = 0; reg < 4; ++reg) {
        int gg = wave * 16 + quad * 4 + reg;
#pragma unroll
        for (int nt = 0; nt < 8; ++nt)
            dst[gg * DIM + nt * 16 + m] = acc[nt][reg];
    }
}

// ------- reduce split-K partials -> P[g]; pooled = (P@W2)/cnt + b2; logits -
__global__ __launch_bounds__(128) void k_final(const float* __restrict__ partial,
                                               const float* __restrict__ W2,
                                               const float* __restrict__ b2,
                                               const float* __restrict__ Wlin,
                                               const float* __restrict__ blin,
                                               const int* __restrict__ batch,
                                               float* __restrict__ out) {
    const int g = blockIdx.x;
    const int t = threadIdx.x;
    int start;
    { int a = 0, b = NN; while (a < b) { int m = (a + b) >> 1; if (batch[m] < g) a = m + 1; else b = m; } start = a; }
    int end;
    { int a = 0, b = NN; while (a < b) { int m = (a + b) >> 1; if (batch[m] < g + 1) a = m + 1; else b = m; } end = a; }
    const int cnt = end - start;

    float s = 0.f;
    for (int b = 0; b < KBLK; b += 4) {
        float s0 = partial[(size_t)(b + 0) * (NG * DIM) + g * DIM + t];
        float s1 = partial[(size_t)(b + 1) * (NG * DIM) + g * DIM + t];
        float s2 = partial[(size_t)(b + 2) * (NG * DIM) + g * DIM + t];
        float s3 = partial[(size_t)(b + 3) * (NG * DIM) + g * DIM + t];
        s += (s0 + s1) + (s2 + s3);
    }
    __shared__ float P[DIM];
    P[t] = s;
    __syncthreads();
    float acc = 0.f;
    for (int k = 0; k < DIM; ++k) acc += P[k] * W2[k * DIM + t];   // fp32 W2
    __shared__ float pooled[DIM];
    pooled[t] = (cnt > 0) ? (acc / (float)cnt + b2[t]) : 0.f;
    __syncthreads();
    if (t < NCLS) {
        float s2 = blin[t];
        for (int k = 0; k < DIM; ++k) s2 += pooled[k] * Wlin[k * NCLS + t];
        out[g * NCLS + t] = s2;
    }
}

extern "C" void kernel_launch(void* const* d_in, const int* in_sizes, int n_in,
                              void* d_out, int out_size, void* d_ws, size_t ws_size,
                              hipStream_t stream) {
    const float* x    = (const float*)d_in[0];
    const float* W1   = (const float*)d_in[1];
    const float* b1   = (const float*)d_in[2];
    const float* W2   = (const float*)d_in[3];
    const float* b2   = (const float*)d_in[4];
    const float* Wlin = (const float*)d_in[5];
    const float* blin = (const float*)d_in[6];
    const int* eidx   = (const int*)d_in[7];   // [2, E] flat: rows then cols
    const int* batch  = (const int*)d_in[8];
    float* out = (float*)d_out;

    char* ws = (char*)d_ws;
    int*    cnt   = (int*)(ws + 0);             // NN ints (zeroed; ends as degree)
    float*  dinv  = (float*)(ws + 200000);      // NN floats (written by gemm1)
    int*    ell   = (int*)(ws + 400000);        // NN*CAP ints = 12.8 MB
    ushort* Wsw   = (ushort*)(ws + 13200000);   // 32768 B (W1 frags)
    float*  Wd    = (float*)(ws + 13232768);    // 64*NNP fp32 = 12845056 B
    uchar*  Hs1   = (uchar*)(ws + 26077824);    // NN*DIM fp8 = 6.4 MB
    ushort* bufB  = (ushort*)(ws + 32477824);   // NNP*DIM bf16 (A2; tail x Wd=0)
    float*  poolpt= (float*)(ws + 45322880);    // KBLK*NG*DIM fp32 = 7.3 MB

    const int* erow = eidx;
    const int* ecol = eidx + NE;

    // ---- structure build: zero+Wprep, single-pass ELL fill ----
    k_init<<<SB + 64 + 784, 256, 0, stream>>>(cnt, W1, Wsw, Wd);
    k_fill<<<E2B, 256, 0, stream>>>(erow, ecol, cnt, ell);

    const int gemm_grid = (NN + 63) / 64;            // 782
    const int node_grid = (NN * 16 + 255) / 256;     // 3125

    // layer 1: Hs1 = fp8(dinv*(x @ W1)) (+dinv table); A2 = relu(dinv*agg + b1)
    k_gemm_mfma<<<gemm_grid, 256, 0, stream>>>(x, Wsw, cnt, Hs1, dinv);
    k_gather_ell<<<node_grid, 256, 0, stream>>>(ell, cnt, b1, Hs1, bufB);

    // layer 2 + pool, fully commuted: P = Wd @ A2 (streaming split-K MFMA)
    k_wbuild<<<E2B + SB, 256, 0, stream>>>(erow, ecol, dinv, batch, Wd);
    k_pool_gemm<<<KBLK, 256, 0, stream>>>(Wd, bufB, poolpt);

    // reduce + P@W2 (fp32) + /cnt + b2 + Wlin head
    k_final<<<NG, 128, 0, stream>>>(poolpt, W2, b2, Wlin, blin, batch, out);
}

// Round 12
// 203.689 us; speedup vs baseline: 3.4781x; 1.0332x over previous
//
#include <hip/hip_runtime.h>

#define NN 50000     // nodes
#define NE 600000    // directed edges (self loops handled separately)
#define NG 64        // graphs
#define DIM 128      // feature dim (D == H == 128)
#define NCLS 10
#define SB 196       // ceil(NN/256)
#define NNP 50176    // SB*256 = 224*224 (padded K for pool GEMM)
#define KBLK 224     // split-K blocks for pool GEMM
#define KCH 224      // K-chunk per block (KBLK*KCH == NNP)
#define CAP 64       // ELL row capacity (multinomial max deg ~33; 64 is safe)
#define E2B ((NE / 2 + 255) / 256)   // edge blocks, 2 edges/thread

typedef unsigned short ushort;
typedef unsigned char uchar;
typedef __attribute__((ext_vector_type(8))) short short8;   // 8 bf16 (4 VGPRs)
typedef __attribute__((ext_vector_type(4))) float float4v;  // 4 fp32 acc
typedef __attribute__((ext_vector_type(2))) float float2v;

__device__ __forceinline__ ushort f2bf(float f) {
    unsigned u = __float_as_uint(f);
    u += 0x7fff + ((u >> 16) & 1);          // RNE
    return (ushort)(u >> 16);
}
// fp8 e4m3 (OCP) encode via HW cvt (RNE, satfinite)
__device__ __forceinline__ uchar f2fp8(float f) {
    int p = __builtin_amdgcn_cvt_pk_fp8_f32(f, f, 0, false);
    return (uchar)(p & 0xff);
}
// decode 8 fp8 (uint2) -> accumulate into a[0..7]
__device__ __forceinline__ void accfp8(float* a, uint2 v) {
    float2v p0 = __builtin_amdgcn_cvt_pk_f32_fp8(v.x, false);
    float2v p1 = __builtin_amdgcn_cvt_pk_f32_fp8(v.x, true);
    float2v p2 = __builtin_amdgcn_cvt_pk_f32_fp8(v.y, false);
    float2v p3 = __builtin_amdgcn_cvt_pk_f32_fp8(v.y, true);
    a[0] += p0[0]; a[1] += p0[1]; a[2] += p1[0]; a[3] += p1[1];
    a[4] += p2[0]; a[5] += p2[1]; a[6] += p3[0]; a[7] += p3[1];
}

// ---- init: zero cnt + W1 frag prep + zero T + zero dinv tail --------------
__global__ void k_init(int* __restrict__ cnt, const float* __restrict__ W1,
                       ushort* __restrict__ Wsw, float* __restrict__ T,
                       float* __restrict__ dinv) {
    int b = blockIdx.x, t = threadIdx.x;
    if (b < SB) {
        int i = b * 256 + t;
        if (i < NN) cnt[i] = 0;
    } else if (b < SB + 64) {
        int tid = (b - SB) * 256 + t;     // 16384 entries
        int j = tid & 7;
        int lane = (tid >> 3) & 63;
        int frag = tid >> 9;              // nt*4+kc
        int nt = frag >> 2, kc = frag & 3;
        int k = kc * 32 + (lane >> 4) * 8 + j;
        int n = nt * 16 + (lane & 15);
        Wsw[tid] = f2bf(W1[k * DIM + n]);
    } else if (b < SB + 64 + 784) {
        // zero T: 64*NNP floats = 802816 float4 = 784 blocks * 256 thr * 4
        float4* w4 = (float4*)T;
        int base = (b - SB - 64) * 256 + t;
#pragma unroll
        for (int i = 0; i < 4; ++i)
            w4[base + i * 200704] = make_float4(0.f, 0.f, 0.f, 0.f);
    } else {
        if (t < NNP - NN) dinv[NN + t] = 0.f;   // pad tail (pool_gemm reads it)
    }
}

// ------- single-pass ELL fill by dst (2 edges/thread); cnt ends as degree --
__global__ void k_fill(const int* __restrict__ row, const int* __restrict__ col,
                       int* __restrict__ cnt, int* __restrict__ ell) {
    int e = (blockIdx.x * blockDim.x + threadIdx.x) * 2;
    if (e < NE) {
        int2 r = *(const int2*)(row + e);
        int2 c = *(const int2*)(col + e);
        int p0 = atomicAdd(&cnt[c.x], 1);
        if (p0 < CAP) ell[c.x * CAP + p0] = r.x;
        int p1 = atomicAdd(&cnt[c.y], 1);
        if (p1 < CAP) ell[c.y * CAP + p1] = r.y;
    }
}

// ---------------- MFMA GEMM: Hs[n,c] = fp8(dinv[n] * sum_k x[n,k] W1[k,c]) -
// Also materializes dinv[n] = rsqrt(1+deg[n]) for pool_gemm reuse.
__global__ __launch_bounds__(256) void k_gemm_mfma(const float* __restrict__ Ain,
                                                   const ushort* __restrict__ Wsw,
                                                   const int* __restrict__ cnt,
                                                   uchar* __restrict__ Hs,
                                                   float* __restrict__ dinv) {
    const int t = threadIdx.x;
    const int wave = t >> 6, lane = t & 63;
    const int m = lane & 15, quad = lane >> 4;
    const int row0 = blockIdx.x * 64 + wave * 16;

    short8 bfrag[8][4];
#pragma unroll
    for (int nt = 0; nt < 8; ++nt)
#pragma unroll
        for (int kc = 0; kc < 4; ++kc)
            bfrag[nt][kc] = *(const short8*)(Wsw + ((nt * 4 + kc) * 64 + lane) * 8);

    float4v acc[8];
#pragma unroll
    for (int nt = 0; nt < 8; ++nt) acc[nt] = (float4v){0.f, 0.f, 0.f, 0.f};

    const int row = row0 + m;
    const int rclamp = row < NN ? row : NN - 1;

#pragma unroll
    for (int kc = 0; kc < 4; ++kc) {
        const float* ap = Ain + (size_t)rclamp * DIM + kc * 32 + quad * 8;
        float4 v0 = *(const float4*)ap;
        float4 v1 = *(const float4*)(ap + 4);
        union { short8 v; ushort u[8]; } tmp;
        tmp.u[0] = f2bf(v0.x); tmp.u[1] = f2bf(v0.y);
        tmp.u[2] = f2bf(v0.z); tmp.u[3] = f2bf(v0.w);
        tmp.u[4] = f2bf(v1.x); tmp.u[5] = f2bf(v1.y);
        tmp.u[6] = f2bf(v1.z); tmp.u[7] = f2bf(v1.w);
        short8 a = tmp.v;
#pragma unroll
        for (int nt = 0; nt < 8; ++nt)
            acc[nt] = __builtin_amdgcn_mfma_f32_16x16x32_bf16(a, bfrag[nt][kc], acc[nt], 0, 0, 0);
    }

    // C/D: col = nt*16 + (lane&15), row = row0 + quad*4 + reg
#pragma unroll
    for (int reg = 0; reg < 4; ++reg) {
        int r = row0 + quad * 4 + reg;
        if (r < NN) {
            float d = rsqrtf(1.0f + (float)cnt[r]);
            if (m == 0) dinv[r] = d;
#pragma unroll
            for (int nt = 0; nt < 8; ++nt)
                Hs[(size_t)r * DIM + nt * 16 + m] = f2fp8(d * acc[nt][reg]);
        }
    }
}

// -------- ELL gather (fp8 in) + fused T-build ------------------------------
// A2 = bf16(relu(dinv[c]*(Hs[c]+sum Hs[r])+b1)); T[batch[c]][r] += dinv[c]
// per edge (and T[batch[c]][c] += dinv[c] self term). 16 lanes/node.
__global__ __launch_bounds__(256) void k_gather_ell(const int* __restrict__ ell,
                                                    const int* __restrict__ deg,
                                                    const int* __restrict__ batch,
                                                    const float* __restrict__ bias,
                                                    const uchar* __restrict__ Hs,
                                                    float* __restrict__ T,
                                                    ushort* __restrict__ out) {
    int gt = blockIdx.x * blockDim.x + threadIdx.x;
    int node = gt >> 4, lane = gt & 15;
    if (node >= NN) return;
    const int* rowp = ell + node * CAP;
    int end = min(deg[node], CAP);
    const float d = rsqrtf(1.0f + (float)end);
    float* Trow = T + (size_t)batch[node] * NNP;
    const size_t off = (size_t)lane * 8;

    float a[8] = {0.f, 0.f, 0.f, 0.f, 0.f, 0.f, 0.f, 0.f};
    accfp8(a, *(const uint2*)(Hs + (size_t)node * DIM + off));   // self loop
    if (lane == 0) atomicAdd(&Trow[node], d);                    // self T term

    int e = 0;
    for (; e + 8 <= end; e += 8) {
        int r0 = rowp[e], r1 = rowp[e + 1], r2 = rowp[e + 2], r3 = rowp[e + 3];
        int r4 = rowp[e + 4], r5 = rowp[e + 5], r6 = rowp[e + 6], r7 = rowp[e + 7];
        if (lane < 8) atomicAdd(&Trow[rowp[e + lane]], d);
        uint2 v0 = *(const uint2*)(Hs + (size_t)r0 * DIM + off);
        uint2 v1 = *(const uint2*)(Hs + (size_t)r1 * DIM + off);
        uint2 v2 = *(const uint2*)(Hs + (size_t)r2 * DIM + off);
        uint2 v3 = *(const uint2*)(Hs + (size_t)r3 * DIM + off);
        uint2 v4 = *(const uint2*)(Hs + (size_t)r4 * DIM + off);
        uint2 v5 = *(const uint2*)(Hs + (size_t)r5 * DIM + off);
        uint2 v6 = *(const uint2*)(Hs + (size_t)r6 * DIM + off);
        uint2 v7 = *(const uint2*)(Hs + (size_t)r7 * DIM + off);
        accfp8(a, v0); accfp8(a, v1); accfp8(a, v2); accfp8(a, v3);
        accfp8(a, v4); accfp8(a, v5); accfp8(a, v6); accfp8(a, v7);
    }
    for (; e + 4 <= end; e += 4) {
        int r0 = rowp[e], r1 = rowp[e + 1], r2 = rowp[e + 2], r3 = rowp[e + 3];
        if (lane < 4) atomicAdd(&Trow[rowp[e + lane]], d);
        uint2 v0 = *(const uint2*)(Hs + (size_t)r0 * DIM + off);
        uint2 v1 = *(const uint2*)(Hs + (size_t)r1 * DIM + off);
        uint2 v2 = *(const uint2*)(Hs + (size_t)r2 * DIM + off);
        uint2 v3 = *(const uint2*)(Hs + (size_t)r3 * DIM + off);
        accfp8(a, v0); accfp8(a, v1); accfp8(a, v2); accfp8(a, v3);
    }
    for (; e < end; ++e) {
        int r = rowp[e];
        if (lane == 0) atomicAdd(&Trow[r], d);
        accfp8(a, *(const uint2*)(Hs + (size_t)r * DIM + off));
    }

    float4 b0 = *(const float4*)(bias + off);
    float4 b1 = *(const float4*)(bias + off + 4);
    a[0] = fmaxf(fmaf(a[0], d, b0.x), 0.f); a[1] = fmaxf(fmaf(a[1], d, b0.y), 0.f);
    a[2] = fmaxf(fmaf(a[2], d, b0.z), 0.f); a[3] = fmaxf(fmaf(a[3], d, b0.w), 0.f);
    a[4] = fmaxf(fmaf(a[4], d, b1.x), 0.f); a[5] = fmaxf(fmaf(a[5], d, b1.y), 0.f);
    a[6] = fmaxf(fmaf(a[6], d, b1.z), 0.f); a[7] = fmaxf(fmaf(a[7], d, b1.w), 0.f);
    uint4 o;
    o.x = (unsigned)f2bf(a[0]) | ((unsigned)f2bf(a[1]) << 16);
    o.y = (unsigned)f2bf(a[2]) | ((unsigned)f2bf(a[3]) << 16);
    o.z = (unsigned)f2bf(a[4]) | ((unsigned)f2bf(a[5]) << 16);
    o.w = (unsigned)f2bf(a[6]) | ((unsigned)f2bf(a[7]) << 16);
    *(uint4*)(out + (size_t)node * DIM + off) = o;
}

// ---------------- pool GEMM: P = (dinv ⊙ T)[64 x NNP] @ A2[NNP x 128] ------
// split-K; all operands streamed sequentially. T zero-padded for k >= NN.
__global__ __launch_bounds__(256) void k_pool_gemm(const float* __restrict__ T,
                                                   const float* __restrict__ dinv,
                                                   const ushort* __restrict__ A2,
                                                   float* __restrict__ partial) {
    const int t = threadIdx.x;
    const int wave = t >> 6, lane = t & 63;
    const int m = lane & 15, quad = lane >> 4;
    const int g = wave * 16 + m;
    const size_t k0 = (size_t)blockIdx.x * KCH;

    float4v acc[8];
#pragma unroll
    for (int nt = 0; nt < 8; ++nt) acc[nt] = (float4v){0.f, 0.f, 0.f, 0.f};

    for (int ks = 0; ks < KCH; ks += 32) {
        const size_t kb = k0 + ks + quad * 8;
        const float* ap = T + (size_t)g * NNP + kb;
        float4 a0 = *(const float4*)ap;
        float4 a1 = *(const float4*)(ap + 4);
        float4 d0 = *(const float4*)(dinv + kb);
        float4 d1 = *(const float4*)(dinv + kb + 4);
        union { short8 v; ushort u[8]; } af;
        af.u[0] = f2bf(a0.x * d0.x); af.u[1] = f2bf(a0.y * d0.y);
        af.u[2] = f2bf(a0.z * d0.z); af.u[3] = f2bf(a0.w * d0.w);
        af.u[4] = f2bf(a1.x * d1.x); af.u[5] = f2bf(a1.y * d1.y);
        af.u[6] = f2bf(a1.z * d1.z); af.u[7] = f2bf(a1.w * d1.w);

        const ushort* bbase = A2 + kb * DIM + m;
#pragma unroll
        for (int nt = 0; nt < 8; ++nt) {
            union { short8 v; ushort u[8]; } bf;
            const ushort* bp = bbase + nt * 16;
#pragma unroll
            for (int j = 0; j < 8; ++j) bf.u[j] = bp[(size_t)j * DIM];
            acc[nt] = __builtin_amdgcn_mfma_f32_16x16x32_bf16(af.v, bf.v, acc[nt], 0, 0, 0);
        }
    }

    float* dst = partial + (size_t)blockIdx.x * (NG * DIM);
#pragma unroll
    for (int reg = 0; reg < 4; ++reg) {
        int gg = wave * 16 + quad * 4 + reg;
#pragma unroll
        for (int nt = 0; nt < 8; ++nt)
            dst[gg * DIM + nt * 16 + m] = acc[nt][reg];
    }
}

// ------- reduce split-K partials -> P[g]; pooled = (P@W2)/cnt + b2; logits -
__global__ __launch_bounds__(128) void k_final(const float* __restrict__ partial,
                                               const float* __restrict__ W2,
                                               const float* __restrict__ b2,
                                               const float* __restrict__ Wlin,
                                               const float* __restrict__ blin,
                                               const int* __restrict__ batch,
                                               float* __restrict__ out) {
    const int g = blockIdx.x;
    const int t = threadIdx.x;
    int start;
    { int a = 0, b = NN; while (a < b) { int m = (a + b) >> 1; if (batch[m] < g) a = m + 1; else b = m; } start = a; }
    int end;
    { int a = 0, b = NN; while (a < b) { int m = (a + b) >> 1; if (batch[m] < g + 1) a = m + 1; else b = m; } end = a; }
    const int cnt = end - start;

    float s = 0.f;
    for (int b = 0; b < KBLK; b += 4) {
        float s0 = partial[(size_t)(b + 0) * (NG * DIM) + g * DIM + t];
        float s1 = partial[(size_t)(b + 1) * (NG * DIM) + g * DIM + t];
        float s2 = partial[(size_t)(b + 2) * (NG * DIM) + g * DIM + t];
        float s3 = partial[(size_t)(b + 3) * (NG * DIM) + g * DIM + t];
        s += (s0 + s1) + (s2 + s3);
    }
    __shared__ float P[DIM];
    P[t] = s;
    __syncthreads();
    float acc = 0.f;
    for (int k = 0; k < DIM; ++k) acc += P[k] * W2[k * DIM + t];   // fp32 W2
    __shared__ float pooled[DIM];
    pooled[t] = (cnt > 0) ? (acc / (float)cnt + b2[t]) : 0.f;
    __syncthreads();
    if (t < NCLS) {
        float s2 = blin[t];
        for (int k = 0; k < DIM; ++k) s2 += pooled[k] * Wlin[k * NCLS + t];
        out[g * NCLS + t] = s2;
    }
}

extern "C" void kernel_launch(void* const* d_in, const int* in_sizes, int n_in,
                              void* d_out, int out_size, void* d_ws, size_t ws_size,
                              hipStream_t stream) {
    const float* x    = (const float*)d_in[0];
    const float* W1   = (const float*)d_in[1];
    const float* b1   = (const float*)d_in[2];
    const float* W2   = (const float*)d_in[3];
    const float* b2   = (const float*)d_in[4];
    const float* Wlin = (const float*)d_in[5];
    const float* blin = (const float*)d_in[6];
    const int* eidx   = (const int*)d_in[7];   // [2, E] flat: rows then cols
    const int* batch  = (const int*)d_in[8];
    float* out = (float*)d_out;

    char* ws = (char*)d_ws;
    int*    cnt   = (int*)(ws + 0);             // NN ints (zeroed; ends as degree)
    float*  dinv  = (float*)(ws + 200000);      // NNP floats (gemm1 writes, tail 0)
    int*    ell   = (int*)(ws + 400704);        // NN*CAP ints = 12.8 MB
    ushort* Wsw   = (ushort*)(ws + 13200704);   // 32768 B (W1 frags)
    float*  T     = (float*)(ws + 13233472);    // 64*NNP fp32 = 12845056 B
    uchar*  Hs1   = (uchar*)(ws + 26078528);    // NN*DIM fp8 = 6.4 MB
    ushort* bufB  = (ushort*)(ws + 32478528);   // NNP*DIM bf16 (A2; tail x T=0)
    float*  poolpt= (float*)(ws + 45323584);    // KBLK*NG*DIM fp32 = 7.3 MB

    const int* erow = eidx;
    const int* ecol = eidx + NE;

    // ---- structure build: zero+Wprep, single-pass ELL fill ----
    k_init<<<SB + 64 + 784 + 1, 256, 0, stream>>>(cnt, W1, Wsw, T, dinv);
    k_fill<<<E2B, 256, 0, stream>>>(erow, ecol, cnt, ell);

    const int gemm_grid = (NN + 63) / 64;            // 782
    const int node_grid = (NN * 16 + 255) / 256;     // 3125

    // layer 1: Hs1 = fp8(dinv*(x @ W1)) (+dinv); A2 = relu(dinv*agg + b1) + T
    k_gemm_mfma<<<gemm_grid, 256, 0, stream>>>(x, Wsw, cnt, Hs1, dinv);
    k_gather_ell<<<node_grid, 256, 0, stream>>>(ell, cnt, batch, b1, Hs1, T, bufB);

    // layer 2 + pool, fully commuted: P = (dinv ⊙ T) @ A2 (streaming split-K)
    k_pool_gemm<<<KBLK, 256, 0, stream>>>(T, dinv, bufB, poolpt);

    // reduce + P@W2 (fp32) + /cnt + b2 + Wlin head
    k_final<<<NG, 128, 0, stream>>>(poolpt, W2, b2, Wlin, blin, batch, out);
}